// Round 6
// baseline (1051.868 us; speedup 1.0000x reference)
//
#include <hip/hip_runtime.h>
#include <hip/hip_bf16.h>
#include <math.h>
#include <stdint.h>

// Problem constants (SelectiveSSM: D_MODEL=1024, D_STATE=16, D_CONV=4, EXPAND=2)
#define B_SZ 4
#define T_SZ 2048
#define DM   1024
#define DI   2048          // D_INNER
#define DS   16            // D_STATE
#define BT   (B_SZ*T_SZ)   // 8192
#define NC   2176          // padded N for fused dt+ssm GEMM (17 x 128)

typedef __attribute__((ext_vector_type(8))) short short8;
typedef __attribute__((ext_vector_type(4))) float f32x4;

__device__ __forceinline__ float siluf(float v) { return v / (1.f + __expf(-v)); }
__device__ __forceinline__ float softplusf(float x) {
    return fmaxf(x, 0.f) + log1pf(__expf(-fabsf(x)));
}
__device__ __forceinline__ unsigned short f2b(float f) {
    __hip_bfloat16 h = __float2bfloat16(f);
    return *reinterpret_cast<unsigned short*>(&h);
}
__device__ __forceinline__ float b2f(unsigned short u) {
    unsigned v = (unsigned)u << 16;
    float f;
    __builtin_memcpy(&f, &v, 4);
    return f;
}

// ---------------------------------------------------------------------------
// fp32 -> bf16 conversion (vectorized x4)
// ---------------------------------------------------------------------------
__global__ __launch_bounds__(256)
void cvt_bf16(const float* __restrict__ src, unsigned short* __restrict__ dst, int n4)
{
    int i = blockIdx.x * 256 + threadIdx.x;
    if (i >= n4) return;
    float4 v = ((const float4*)src)[i];
    ushort4 o;
    o.x = f2b(v.x); o.y = f2b(v.y); o.z = f2b(v.z); o.w = f2b(v.w);
    ((ushort4*)dst)[i] = o;
}

// Pack W_dt (2048xK) + W_x (32xK) + zero pad into Wcb (2176xK) bf16
__global__ __launch_bounds__(256)
void cvt_wc(const float* __restrict__ Wdt, const float* __restrict__ Wx,
            unsigned short* __restrict__ dst)
{
    const int n4 = NC * (DI / 4);          // 2176*512
    int i = blockIdx.x * 256 + threadIdx.x;
    if (i >= n4) return;
    int row = i >> 9;                      // / (2048/4)
    int c4  = i & 511;
    float4 v;
    if (row < 2048)      v = ((const float4*)Wdt)[(size_t)row * 512 + c4];
    else if (row < 2080) v = ((const float4*)Wx)[(size_t)(row - 2048) * 512 + c4];
    else                 v = make_float4(0.f, 0.f, 0.f, 0.f);
    ushort4 o;
    o.x = f2b(v.x); o.y = f2b(v.y); o.z = f2b(v.z); o.w = f2b(v.w);
    ((ushort4*)dst)[i] = o;
}

// ---------------------------------------------------------------------------
// bf16 MFMA GEMM v4 — "flat" (NO LDS): C[m,n] = sum_k A[m,k]*B[n,k],
// A: MxK, B: NxK, row-major (K contiguous). In NT layout the 16x16x32 MFMA
// fragments are 16B-contiguous runs along K, so each lane loads its fragment
// DIRECTLY from global (global_load_dwordx4) — no LDS staging, no barriers,
// no vmcnt(0) drains, no bank conflicts. Reuse comes from L1 (A rows shared
// by 2 waves within the block) and L2 (B tiles shared across the GROUP_M=16
// dispatch cohort). 2-deep software pipeline: prefetch k+32 frags while
// doing MFMAs on k. 256 thr = 4 waves (2x2), 64x64 wave-tile, 16 MFMA per
// 8 fragment loads (0.5 KiB/MFMA).
// mode 0: bf16 split store  cols<2048 -> o0, else -> o1 (both ldc 2048)
// mode 1: cols<2048 -> softplus(v+bias[col]) fp32 o0 (ldc 2048);
//         2048..2063 -> o1[row*16+c]; 2064..2079 -> o2[row*16+c]; >=2080 drop
// mode 2: fp32 plain store to o0, ldc = N
// ---------------------------------------------------------------------------
__global__ __launch_bounds__(256, 3)
void gemm_mfma(const unsigned short* __restrict__ A,
               const unsigned short* __restrict__ Bm,
               int M, int N, int K, int mode,
               const float* __restrict__ bias,
               void* __restrict__ o0, void* __restrict__ o1, void* __restrict__ o2)
{
    // GROUP_M swizzle (GM=16 divides npm=64 for all three GEMMs here)
    const int npn = N >> 7;
    const int pid = blockIdx.x;
    const int gsz = 16 * npn;
    const int gid = pid / gsz;
    const int pm  = gid * 16 + (pid % 16);
    const int pn  = (pid % gsz) / 16;
    const int bm  = pm * 128;
    const int bn  = pn * 128;

    const int tid  = threadIdx.x;
    const int lane = tid & 63;
    const int wave = tid >> 6;          // 0..3
    const int wm   = (wave >> 1) * 64;
    const int wn   = (wave & 1) * 64;
    const int fr   = lane & 15;         // row within 16-tile
    const int fk   = (lane >> 4) * 8;   // k offset within 32

    const unsigned short* Ap = A  + (size_t)(bm + wm + fr) * K + fk;
    const unsigned short* Bp = Bm + (size_t)(bn + wn + fr) * K + fk;
    const size_t r16 = (size_t)16 * K;  // 16-row stride

    f32x4 zero4 = {0.f, 0.f, 0.f, 0.f};
    f32x4 acc[4][4];
#pragma unroll
    for (int i = 0; i < 4; i++)
#pragma unroll
        for (int j = 0; j < 4; j++) acc[i][j] = zero4;

    short8 a0[4], b0[4], a1[4], b1[4];
#pragma unroll
    for (int i = 0; i < 4; i++) {
        a0[i] = *(const short8*)(Ap + i * r16);
        b0[i] = *(const short8*)(Bp + i * r16);
    }

    for (int k0 = 0; k0 < K; k0 += 64) {
        // prefetch second half-iter fragments (k0+32)
#pragma unroll
        for (int i = 0; i < 4; i++) {
            a1[i] = *(const short8*)(Ap + i * r16 + k0 + 32);
            b1[i] = *(const short8*)(Bp + i * r16 + k0 + 32);
        }
        // MFMAs on k0 fragments
#pragma unroll
        for (int i = 0; i < 4; i++)
#pragma unroll
            for (int j = 0; j < 4; j++)
                acc[i][j] = __builtin_amdgcn_mfma_f32_16x16x32_bf16(
                    a0[i], b0[j], acc[i][j], 0, 0, 0);
        // prefetch next iteration's first half (k0+64)
        if (k0 + 64 < K) {
#pragma unroll
            for (int i = 0; i < 4; i++) {
                a0[i] = *(const short8*)(Ap + i * r16 + k0 + 64);
                b0[i] = *(const short8*)(Bp + i * r16 + k0 + 64);
            }
        }
        // MFMAs on k0+32 fragments
#pragma unroll
        for (int i = 0; i < 4; i++)
#pragma unroll
            for (int j = 0; j < 4; j++)
                acc[i][j] = __builtin_amdgcn_mfma_f32_16x16x32_bf16(
                    a1[i], b1[j], acc[i][j], 0, 0, 0);
    }

    // epilogue. C/D layout: col = lane&15, row = (lane>>4)*4 + r  [m89/m91]
    const int cr0 = bm + wm + (lane >> 4) * 4;
    const int cc0 = bn + wn + (lane & 15);
#pragma unroll
    for (int i = 0; i < 4; i++) {
#pragma unroll
        for (int j = 0; j < 4; j++) {
            const int col = cc0 + j * 16;
#pragma unroll
            for (int r = 0; r < 4; r++) {
                const int row = cr0 + i * 16 + r;
                float v = acc[i][j][r];
                if (mode == 0) {
                    if (col < 2048)
                        ((unsigned short*)o0)[(size_t)row * 2048 + col] = f2b(v);
                    else
                        ((unsigned short*)o1)[(size_t)row * 2048 + col - 2048] = f2b(v);
                } else if (mode == 1) {
                    if (col < 2048) {
                        ((float*)o0)[(size_t)row * 2048 + col] = softplusf(v + bias[col]);
                    } else if (col < 2064) {
                        ((float*)o1)[(size_t)row * DS + (col - 2048)] = v;
                    } else if (col < 2080) {
                        ((float*)o2)[(size_t)row * DS + (col - 2064)] = v;
                    }
                } else {
                    ((float*)o0)[(size_t)row * N + col] = v;
                }
            }
        }
    }
}

// ---------------------------------------------------------------------------
// Depthwise causal conv (width 4) + SiLU, bf16 in -> bf16 out.
// ---------------------------------------------------------------------------
__global__ __launch_bounds__(256)
void conv_silu(const unsigned short* __restrict__ xpb, const float* __restrict__ cw,
               const float* __restrict__ cb, unsigned short* __restrict__ xcb)
{
    const int idx = blockIdx.x * 256 + threadIdx.x;   // over BT*DI
    const int i  = idx & (DI - 1);
    const int bt = idx >> 11;
    const int t  = bt & (T_SZ - 1);
    float acc = cb[i];
    float4 w = *(const float4*)(cw + (size_t)i * 4);
    float wr[4] = {w.x, w.y, w.z, w.w};
#pragma unroll
    for (int k = 0; k < 4; k++) {
        const int tt = t - 3 + k;
        if (tt >= 0)
            acc = fmaf(b2f(xpb[(size_t)(bt - 3 + k) * DI + i]), wr[k], acc);
    }
    xcb[idx] = f2b(siluf(acc));
}

// ---------------------------------------------------------------------------
// Chunked parallel selective scan. Block: 16 chunks x 16 d-cols = 256 thr.
// Grid: (DI/16, B). Phase1: per-chunk (h_end, prod dA) from h0=0.
// Phase2: LDS carry combine. Phase3: replay with corrected h0, y in-place.
// ---------------------------------------------------------------------------
#define CH 16
#define CL (T_SZ / CH)   // 128

__global__ __launch_bounds__(256)
void scan2(const unsigned short* __restrict__ xcb, float* __restrict__ dty,
           const float* __restrict__ Bp, const float* __restrict__ Cp,
           const float* __restrict__ A_log)
{
    __shared__ float shH[CH][16][DS];
    __shared__ float shP[CH][16][DS];
    __shared__ float shI[CH][16][DS];
    const int tid = threadIdx.x;
    const int c = tid >> 4;
    const int g = tid & 15;
    const int b = blockIdx.y;
    const int d = blockIdx.x * 16 + g;

    float A[DS];
#pragma unroll
    for (int s = 0; s < DS; s++) A[s] = -__expf(A_log[s]);

    const size_t colbase = (size_t)b * T_SZ * DI + d;
    const unsigned short* xp = xcb + colbase + (size_t)c * CL * DI;
    float* dp = dty + colbase + (size_t)c * CL * DI;
    const float4* Bb = (const float4*)(Bp + ((size_t)b * T_SZ + c * CL) * DS);
    const float4* Cb = (const float4*)(Cp + ((size_t)b * T_SZ + c * CL) * DS);

    float h[DS], P[DS];
#pragma unroll
    for (int s = 0; s < DS; s++) { h[s] = 0.f; P[s] = 1.f; }

    for (int i = 0; i < CL; i++) {
        const float xv = b2f(xp[(size_t)i * DI]);
        const float dv = dp[(size_t)i * DI];
        float4 Bv[4] = {Bb[i*4+0], Bb[i*4+1], Bb[i*4+2], Bb[i*4+3]};
        const float* bs = (const float*)&Bv[0];
        const float dx = dv * xv;
#pragma unroll
        for (int s = 0; s < DS; s++) {
            const float dA = __expf(dv * A[s]);
            h[s] = fmaf(dA, h[s], dx * bs[s]);
            P[s] *= dA;
        }
    }
#pragma unroll
    for (int s = 0; s < DS; s += 4) {
        *(float4*)&shH[c][g][s] = make_float4(h[s], h[s+1], h[s+2], h[s+3]);
        *(float4*)&shP[c][g][s] = make_float4(P[s], P[s+1], P[s+2], P[s+3]);
    }
    __syncthreads();

    {
        const int g2 = tid >> 4, s2 = tid & 15;
        float hin = 0.f;
        shI[0][g2][s2] = 0.f;
        for (int cc = 1; cc < CH; cc++) {
            hin = fmaf(shP[cc-1][g2][s2], hin, shH[cc-1][g2][s2]);
            shI[cc][g2][s2] = hin;
        }
    }
    __syncthreads();

#pragma unroll
    for (int s = 0; s < DS; s++) h[s] = shI[c][g][s];
    for (int i = 0; i < CL; i++) {
        const float xv = b2f(xp[(size_t)i * DI]);
        const float dv = dp[(size_t)i * DI];
        float4 Bv[4] = {Bb[i*4+0], Bb[i*4+1], Bb[i*4+2], Bb[i*4+3]};
        float4 Cv[4] = {Cb[i*4+0], Cb[i*4+1], Cb[i*4+2], Cb[i*4+3]};
        const float* bs = (const float*)&Bv[0];
        const float* cs = (const float*)&Cv[0];
        const float dx = dv * xv;
        float yv = 0.f;
#pragma unroll
        for (int s = 0; s < DS; s++) {
            const float dA = __expf(dv * A[s]);
            h[s] = fmaf(dA, h[s], dx * bs[s]);
            yv = fmaf(h[s], cs[s], yv);
        }
        dp[(size_t)i * DI] = yv;   // overwrites dt[t] after its last use
    }
}

// ---------------------------------------------------------------------------
// Fused LayerNorm + xc*D residual + silu(z) gate. y fp32 in, yb bf16 out.
// ---------------------------------------------------------------------------
__global__ __launch_bounds__(256)
void ln_fuse(const float* __restrict__ y, const unsigned short* __restrict__ xcb,
             const unsigned short* __restrict__ zb, const float* __restrict__ g,
             const float* __restrict__ bln, const float* __restrict__ Dp,
             unsigned short* __restrict__ yb)
{
    __shared__ float rs[256], rss[256];
    const int bt  = blockIdx.x;
    const int tid = threadIdx.x;
    const float* yr = y + (size_t)bt * DI;
    const unsigned short* xr = xcb + (size_t)bt * DI;
    const unsigned short* zr = zb + (size_t)bt * DI;
    unsigned short* orow = yb + (size_t)bt * DI;

    float v[8];
    float s = 0.f, ss = 0.f;
#pragma unroll
    for (int j = 0; j < 8; j++) {
        v[j] = yr[tid + j * 256];
        s  += v[j];
        ss += v[j] * v[j];
    }
    rs[tid] = s; rss[tid] = ss;
    __syncthreads();
    for (int off = 128; off > 0; off >>= 1) {
        if (tid < off) { rs[tid] += rs[tid + off]; rss[tid] += rss[tid + off]; }
        __syncthreads();
    }
    const float mu   = rs[0] * (1.f / DI);
    const float var  = rss[0] * (1.f / DI) - mu * mu;
    const float rstd = rsqrtf(var + 1e-5f);
#pragma unroll
    for (int j = 0; j < 8; j++) {
        const int dcol = tid + j * 256;
        float yn = (v[j] - mu) * rstd * g[dcol] + bln[dcol];
        yn += b2f(xr[dcol]) * Dp[dcol];
        yn *= siluf(b2f(zr[dcol]));
        orow[dcol] = f2b(yn);
    }
}

// ---------------------------------------------------------------------------
// Workspace layout (MiB offsets, total ~175 MiB):
//   [  0, 32)  xpb bf16  (G1 out) -> dead after conv -> yb bf16 (ln out)
//   [ 32, 64)  zb  bf16
//   [ 64, 96)  xcb bf16
//   [ 96,160)  dts fp32 (G3 out) -> y fp32 (scan, in-place)
//       [ 96,112) xb bf16   (dead before G3 writes dts)
//       [112,120) W_inb bf16 (dead before G3)
//   [160,169)  Wcb bf16 (2176x2048: W_dt | W_x | zeros)
//   [169,173)  W_outb bf16
//   [174,175)  Bp, Cp fp32
// ---------------------------------------------------------------------------
extern "C" void kernel_launch(void* const* d_in, const int* in_sizes, int n_in,
                              void* d_out, int out_size, void* d_ws, size_t ws_size,
                              hipStream_t stream)
{
    const float* x      = (const float*)d_in[0];
    const float* W_in   = (const float*)d_in[1];
    const float* conv_w = (const float*)d_in[2];
    const float* conv_b = (const float*)d_in[3];
    const float* W_x    = (const float*)d_in[4];
    const float* W_dt   = (const float*)d_in[5];
    const float* b_dt   = (const float*)d_in[6];
    const float* A_log  = (const float*)d_in[7];
    const float* D_par  = (const float*)d_in[8];
    const float* W_out  = (const float*)d_in[9];
    const float* ln_g   = (const float*)d_in[10];
    const float* ln_b   = (const float*)d_in[11];
    float* out = (float*)d_out;

    char* w = (char*)d_ws;
    const size_t MB = 1ull << 20;
    unsigned short* xpb    = (unsigned short*)(w);
    unsigned short* zb     = (unsigned short*)(w + 32 * MB);
    unsigned short* xcb    = (unsigned short*)(w + 64 * MB);
    float*          dts    = (float*)(w + 96 * MB);
    unsigned short* xb     = (unsigned short*)(w + 96 * MB);
    unsigned short* W_inb  = (unsigned short*)(w + 112 * MB);
    unsigned short* Wcb    = (unsigned short*)(w + 160 * MB);
    unsigned short* W_outb = (unsigned short*)(w + 169 * MB);
    float*          BpF    = (float*)(w + 174 * MB);
    float*          CpF    = BpF + (size_t)BT * DS;
    unsigned short* yb     = xpb;   // reuse after conv

    dim3 blk(256);

    // conversions to bf16
    cvt_bf16<<<dim3((BT * DM / 4 + 255) / 256), blk, 0, stream>>>(x, xb, BT * DM / 4);
    cvt_bf16<<<dim3((2 * DI * DM / 4 + 255) / 256), blk, 0, stream>>>(W_in, W_inb, 2 * DI * DM / 4);
    cvt_wc<<<dim3((NC * DI / 4 + 255) / 256), blk, 0, stream>>>(W_dt, W_x, Wcb);
    cvt_bf16<<<dim3((DM * DI / 4 + 255) / 256), blk, 0, stream>>>(W_out, W_outb, DM * DI / 4);

    // 1) xz = x @ W_in^T -> split bf16 xpb | zb
    gemm_mfma<<<dim3((BT / 128) * (2 * DI / 128)), blk, 0, stream>>>(
        xb, W_inb, BT, 2 * DI, DM, 0, nullptr, xpb, zb, nullptr);

    // 2) depthwise conv + silu -> xcb bf16
    conv_silu<<<dim3(BT * DI / 256), blk, 0, stream>>>(xpb, conv_w, conv_b, xcb);

    // 3) fused dt+ssm GEMM: [W_dt | W_x] -> dts fp32 (softplus+bias), Bp, Cp
    gemm_mfma<<<dim3((BT / 128) * (NC / 128)), blk, 0, stream>>>(
        xcb, Wcb, BT, NC, DI, 1, b_dt, dts, BpF, CpF);

    // 4) chunked parallel scan -> y fp32 (in-place over dts)
    scan2<<<dim3(DI / 16, B_SZ), blk, 0, stream>>>(xcb, dts, BpF, CpF, A_log);

    // 5) LayerNorm + residual + gate -> yb bf16
    ln_fuse<<<dim3(BT), blk, 0, stream>>>(dts, xcb, zb, ln_g, ln_b, D_par, yb);

    // 6) out = y @ W_out^T -> fp32
    gemm_mfma<<<dim3((BT / 128) * (DM / 128)), blk, 0, stream>>>(
        yb, W_outb, BT, DM, DI, 2, nullptr, out, nullptr, nullptr);
}

// Round 7
// 700.696 us; speedup vs baseline: 1.5012x; 1.5012x over previous
//
#include <hip/hip_runtime.h>
#include <hip/hip_bf16.h>
#include <math.h>
#include <stdint.h>

// Problem constants (SelectiveSSM: D_MODEL=1024, D_STATE=16, D_CONV=4, EXPAND=2)
#define B_SZ 4
#define T_SZ 2048
#define DM   1024
#define DI   2048          // D_INNER
#define DS   16            // D_STATE
#define BT   (B_SZ*T_SZ)   // 8192
#define NC   2176          // padded N for fused dt+ssm GEMM (17 x 128)

typedef __attribute__((ext_vector_type(8))) short short8;
typedef __attribute__((ext_vector_type(4))) float f32x4;

__device__ __forceinline__ float siluf(float v) { return v / (1.f + __expf(-v)); }
__device__ __forceinline__ float softplusf(float x) {
    return fmaxf(x, 0.f) + log1pf(__expf(-fabsf(x)));
}
__device__ __forceinline__ unsigned short f2b(float f) {
    __hip_bfloat16 h = __float2bfloat16(f);
    return *reinterpret_cast<unsigned short*>(&h);
}
__device__ __forceinline__ float b2f(unsigned short u) {
    unsigned v = (unsigned)u << 16;
    float f;
    __builtin_memcpy(&f, &v, 4);
    return f;
}
__device__ __forceinline__ void gld_lds16(const void* g, void* l) {
    __builtin_amdgcn_global_load_lds(
        (const __attribute__((address_space(1))) unsigned int*)g,
        (__attribute__((address_space(3))) unsigned int*)l,
        16, 0, 0);
}

// ---------------------------------------------------------------------------
// fp32 -> bf16 conversion (vectorized x4)
// ---------------------------------------------------------------------------
__global__ __launch_bounds__(256)
void cvt_bf16(const float* __restrict__ src, unsigned short* __restrict__ dst, int n4)
{
    int i = blockIdx.x * 256 + threadIdx.x;
    if (i >= n4) return;
    float4 v = ((const float4*)src)[i];
    ushort4 o;
    o.x = f2b(v.x); o.y = f2b(v.y); o.z = f2b(v.z); o.w = f2b(v.w);
    ((ushort4*)dst)[i] = o;
}

// Pack W_dt (2048xK) + W_x (32xK) + zero pad into Wcb (2176xK) bf16
__global__ __launch_bounds__(256)
void cvt_wc(const float* __restrict__ Wdt, const float* __restrict__ Wx,
            unsigned short* __restrict__ dst)
{
    const int n4 = NC * (DI / 4);          // 2176*512
    int i = blockIdx.x * 256 + threadIdx.x;
    if (i >= n4) return;
    int row = i >> 9;                      // / (2048/4)
    int c4  = i & 511;
    float4 v;
    if (row < 2048)      v = ((const float4*)Wdt)[(size_t)row * 512 + c4];
    else if (row < 2080) v = ((const float4*)Wx)[(size_t)(row - 2048) * 512 + c4];
    else                 v = make_float4(0.f, 0.f, 0.f, 0.f);
    ushort4 o;
    o.x = f2b(v.x); o.y = f2b(v.y); o.z = f2b(v.z); o.w = f2b(v.w);
    ((ushort4*)dst)[i] = o;
}

// ---------------------------------------------------------------------------
// bf16 MFMA GEMM v5: C[m,n] = sum_k A[m,k]*B[n,k], A: MxK, B: NxK, row-major.
// 256x128 block tile, 512 threads = 8 waves (4x2), 64x64 wave-tile (16 MFMA
// per 8 ds_read_b128 = 512 B/MFMA LDS traffic). BK=32, LDS double-buffer,
// ONE barrier per K-iter (prefetch via global_load_lds issued before the
// MFMA phase; the barrier's vmcnt drain is covered by compute).
// XOR BANK SWIZZLE: 16B chunk j of row r is stored at chunk-slot
// cs = j ^ ((r>>1)&3). Fragment-read start banks then spread over 8
// positions (2 lanes/start = conflict-free, m136) instead of 2 (8-way).
// global_load_lds writes are lane-linear (unchanged); the swizzle is applied
// to the global SOURCE address each lane loads.
// 1D grid + GROUP_M=16 swizzle for B-tile L2 reuse.
// mode 0: bf16 split store  cols<2048 -> o0, else -> o1 (both ldc 2048)
// mode 1: cols<2048 -> softplus(v+bias[col]) fp32 o0 (ldc 2048);
//         2048..2063 -> o1[row*16+c]; 2064..2079 -> o2[row*16+c]; >=2080 drop
// mode 2: fp32 plain store to o0, ldc = N
// ---------------------------------------------------------------------------
__global__ __launch_bounds__(512)
void gemm_mfma(const unsigned short* __restrict__ A,
               const unsigned short* __restrict__ Bm,
               int M, int N, int K, int mode,
               const float* __restrict__ bias,
               void* __restrict__ o0, void* __restrict__ o1, void* __restrict__ o2)
{
    __shared__ unsigned short As[2][256 * 32];   // 2 x 16 KB
    __shared__ unsigned short Bs[2][128 * 32];   // 2 x  8 KB  (48 KB total)

    // GROUP_M swizzle (npm = M/256 = 32 for all GEMMs here; GM=16 divides it)
    const int npn = N >> 7;
    const int pid = blockIdx.x;
    const int gsz = 16 * npn;
    const int gid = pid / gsz;
    const int pm  = gid * 16 + (pid % 16);
    const int pn  = (pid % gsz) / 16;
    const int bm  = pm * 256;
    const int bn  = pn * 128;

    const int tid  = threadIdx.x;
    const int lane = tid & 63;
    const int wave = tid >> 6;          // 0..7
    const int wm   = (wave >> 1) * 64;  // {0,64,128,192}
    const int wn   = (wave & 1) * 64;   // {0,64}
    const int fr   = lane & 15;         // row within 16-tile
    const int fj   = lane >> 4;         // k-chunk 0..3 (8 elems each)

    f32x4 zero4 = {0.f, 0.f, 0.f, 0.f};
    f32x4 acc[4][4];
#pragma unroll
    for (int i = 0; i < 4; i++)
#pragma unroll
        for (int j = 0; j < 4; j++) acc[i][j] = zero4;

    // --- staging source pointers (swizzled chunk per slot) ---
    // A: slots q*512+tid (q=0,1) cover 256 rows x 4 chunks
    const unsigned short* AgP[2];
#pragma unroll
    for (int q = 0; q < 2; q++) {
        const int slot = q * 512 + tid;
        const int row  = slot >> 2;
        const int j    = (slot & 3) ^ ((row >> 1) & 3);
        AgP[q] = A + (size_t)(bm + row) * K + j * 8;
    }
    const int rowB = tid >> 2;
    const int jB   = (tid & 3) ^ ((rowB >> 1) & 3);
    const unsigned short* BgP = Bm + (size_t)(bn + rowB) * K + jB * 8;

    // --- fragment LDS element offsets (loop-invariant, swizzled) ---
    int aoff[4], boff[4];
#pragma unroll
    for (int i = 0; i < 4; i++) {
        const int r = wm + i * 16 + fr;
        aoff[i] = r * 32 + ((fj ^ ((r >> 1) & 3)) * 8);
    }
#pragma unroll
    for (int j = 0; j < 4; j++) {
        const int r = wn + j * 16 + fr;
        boff[j] = r * 32 + ((fj ^ ((r >> 1) & 3)) * 8);
    }

    // prologue: stage k=0 into buf 0
    gld_lds16(AgP[0], &As[0][tid * 8]);
    gld_lds16(AgP[1], &As[0][(512 + tid) * 8]);
    gld_lds16(BgP,    &Bs[0][tid * 8]);
    __syncthreads();

    int cur = 0;
    for (int k0 = 0; k0 < K; k0 += 32) {
        if (k0 + 32 < K) {
            gld_lds16(AgP[0] + k0 + 32, &As[cur ^ 1][tid * 8]);
            gld_lds16(AgP[1] + k0 + 32, &As[cur ^ 1][(512 + tid) * 8]);
            gld_lds16(BgP    + k0 + 32, &Bs[cur ^ 1][tid * 8]);
        }
        short8 af[4], bf[4];
#pragma unroll
        for (int i = 0; i < 4; i++) af[i] = *(const short8*)&As[cur][aoff[i]];
#pragma unroll
        for (int j = 0; j < 4; j++) bf[j] = *(const short8*)&Bs[cur][boff[j]];
#pragma unroll
        for (int i = 0; i < 4; i++)
#pragma unroll
            for (int j = 0; j < 4; j++)
                acc[i][j] = __builtin_amdgcn_mfma_f32_16x16x32_bf16(
                    af[i], bf[j], acc[i][j], 0, 0, 0);
        __syncthreads();   // drains prefetch (vmcnt) + protects cur buffer
        cur ^= 1;
    }

    // epilogue. C/D layout: col = lane&15, row = (lane>>4)*4 + r  [m89/m91]
    const int cr0 = bm + wm + (lane >> 4) * 4;
    const int cc0 = bn + wn + (lane & 15);
#pragma unroll
    for (int i = 0; i < 4; i++) {
#pragma unroll
        for (int j = 0; j < 4; j++) {
            const int col = cc0 + j * 16;
#pragma unroll
            for (int r = 0; r < 4; r++) {
                const int row = cr0 + i * 16 + r;
                float v = acc[i][j][r];
                if (mode == 0) {
                    if (col < 2048)
                        ((unsigned short*)o0)[(size_t)row * 2048 + col] = f2b(v);
                    else
                        ((unsigned short*)o1)[(size_t)row * 2048 + col - 2048] = f2b(v);
                } else if (mode == 1) {
                    if (col < 2048) {
                        ((float*)o0)[(size_t)row * 2048 + col] = softplusf(v + bias[col]);
                    } else if (col < 2064) {
                        ((float*)o1)[(size_t)row * DS + (col - 2048)] = v;
                    } else if (col < 2080) {
                        ((float*)o2)[(size_t)row * DS + (col - 2064)] = v;
                    }
                } else {
                    ((float*)o0)[(size_t)row * N + col] = v;
                }
            }
        }
    }
}

// ---------------------------------------------------------------------------
// Depthwise causal conv (width 4) + SiLU, bf16 in -> bf16 out.
// ---------------------------------------------------------------------------
__global__ __launch_bounds__(256)
void conv_silu(const unsigned short* __restrict__ xpb, const float* __restrict__ cw,
               const float* __restrict__ cb, unsigned short* __restrict__ xcb)
{
    const int idx = blockIdx.x * 256 + threadIdx.x;   // over BT*DI
    const int i  = idx & (DI - 1);
    const int bt = idx >> 11;
    const int t  = bt & (T_SZ - 1);
    float acc = cb[i];
    float4 w = *(const float4*)(cw + (size_t)i * 4);
    float wr[4] = {w.x, w.y, w.z, w.w};
#pragma unroll
    for (int k = 0; k < 4; k++) {
        const int tt = t - 3 + k;
        if (tt >= 0)
            acc = fmaf(b2f(xpb[(size_t)(bt - 3 + k) * DI + i]), wr[k], acc);
    }
    xcb[idx] = f2b(siluf(acc));
}

// ---------------------------------------------------------------------------
// Chunked parallel selective scan. Block: 16 chunks x 16 d-cols = 256 thr.
// Grid: (DI/16, B). Phase1: per-chunk (h_end, prod dA) from h0=0.
// Phase2: LDS carry combine. Phase3: replay with corrected h0, y in-place.
// ---------------------------------------------------------------------------
#define CH 16
#define CL (T_SZ / CH)   // 128

__global__ __launch_bounds__(256)
void scan2(const unsigned short* __restrict__ xcb, float* __restrict__ dty,
           const float* __restrict__ Bp, const float* __restrict__ Cp,
           const float* __restrict__ A_log)
{
    __shared__ float shH[CH][16][DS];
    __shared__ float shP[CH][16][DS];
    __shared__ float shI[CH][16][DS];
    const int tid = threadIdx.x;
    const int c = tid >> 4;
    const int g = tid & 15;
    const int b = blockIdx.y;
    const int d = blockIdx.x * 16 + g;

    float A[DS];
#pragma unroll
    for (int s = 0; s < DS; s++) A[s] = -__expf(A_log[s]);

    const size_t colbase = (size_t)b * T_SZ * DI + d;
    const unsigned short* xp = xcb + colbase + (size_t)c * CL * DI;
    float* dp = dty + colbase + (size_t)c * CL * DI;
    const float4* Bb = (const float4*)(Bp + ((size_t)b * T_SZ + c * CL) * DS);
    const float4* Cb = (const float4*)(Cp + ((size_t)b * T_SZ + c * CL) * DS);

    float h[DS], P[DS];
#pragma unroll
    for (int s = 0; s < DS; s++) { h[s] = 0.f; P[s] = 1.f; }

    for (int i = 0; i < CL; i++) {
        const float xv = b2f(xp[(size_t)i * DI]);
        const float dv = dp[(size_t)i * DI];
        float4 Bv[4] = {Bb[i*4+0], Bb[i*4+1], Bb[i*4+2], Bb[i*4+3]};
        const float* bs = (const float*)&Bv[0];
        const float dx = dv * xv;
#pragma unroll
        for (int s = 0; s < DS; s++) {
            const float dA = __expf(dv * A[s]);
            h[s] = fmaf(dA, h[s], dx * bs[s]);
            P[s] *= dA;
        }
    }
#pragma unroll
    for (int s = 0; s < DS; s += 4) {
        *(float4*)&shH[c][g][s] = make_float4(h[s], h[s+1], h[s+2], h[s+3]);
        *(float4*)&shP[c][g][s] = make_float4(P[s], P[s+1], P[s+2], P[s+3]);
    }
    __syncthreads();

    {
        const int g2 = tid >> 4, s2 = tid & 15;
        float hin = 0.f;
        shI[0][g2][s2] = 0.f;
        for (int cc = 1; cc < CH; cc++) {
            hin = fmaf(shP[cc-1][g2][s2], hin, shH[cc-1][g2][s2]);
            shI[cc][g2][s2] = hin;
        }
    }
    __syncthreads();

#pragma unroll
    for (int s = 0; s < DS; s++) h[s] = shI[c][g][s];
    for (int i = 0; i < CL; i++) {
        const float xv = b2f(xp[(size_t)i * DI]);
        const float dv = dp[(size_t)i * DI];
        float4 Bv[4] = {Bb[i*4+0], Bb[i*4+1], Bb[i*4+2], Bb[i*4+3]};
        float4 Cv[4] = {Cb[i*4+0], Cb[i*4+1], Cb[i*4+2], Cb[i*4+3]};
        const float* bs = (const float*)&Bv[0];
        const float* cs = (const float*)&Cv[0];
        const float dx = dv * xv;
        float yv = 0.f;
#pragma unroll
        for (int s = 0; s < DS; s++) {
            const float dA = __expf(dv * A[s]);
            h[s] = fmaf(dA, h[s], dx * bs[s]);
            yv = fmaf(h[s], cs[s], yv);
        }
        dp[(size_t)i * DI] = yv;   // overwrites dt[t] after its last use
    }
}

// ---------------------------------------------------------------------------
// Fused LayerNorm + xc*D residual + silu(z) gate. y fp32 in, yb bf16 out.
// ---------------------------------------------------------------------------
__global__ __launch_bounds__(256)
void ln_fuse(const float* __restrict__ y, const unsigned short* __restrict__ xcb,
             const unsigned short* __restrict__ zb, const float* __restrict__ g,
             const float* __restrict__ bln, const float* __restrict__ Dp,
             unsigned short* __restrict__ yb)
{
    __shared__ float rs[256], rss[256];
    const int bt  = blockIdx.x;
    const int tid = threadIdx.x;
    const float* yr = y + (size_t)bt * DI;
    const unsigned short* xr = xcb + (size_t)bt * DI;
    const unsigned short* zr = zb + (size_t)bt * DI;
    unsigned short* orow = yb + (size_t)bt * DI;

    float v[8];
    float s = 0.f, ss = 0.f;
#pragma unroll
    for (int j = 0; j < 8; j++) {
        v[j] = yr[tid + j * 256];
        s  += v[j];
        ss += v[j] * v[j];
    }
    rs[tid] = s; rss[tid] = ss;
    __syncthreads();
    for (int off = 128; off > 0; off >>= 1) {
        if (tid < off) { rs[tid] += rs[tid + off]; rss[tid] += rss[tid + off]; }
        __syncthreads();
    }
    const float mu   = rs[0] * (1.f / DI);
    const float var  = rss[0] * (1.f / DI) - mu * mu;
    const float rstd = rsqrtf(var + 1e-5f);
#pragma unroll
    for (int j = 0; j < 8; j++) {
        const int dcol = tid + j * 256;
        float yn = (v[j] - mu) * rstd * g[dcol] + bln[dcol];
        yn += b2f(xr[dcol]) * Dp[dcol];
        yn *= siluf(b2f(zr[dcol]));
        orow[dcol] = f2b(yn);
    }
}

// ---------------------------------------------------------------------------
// Workspace layout (MiB offsets, total ~175 MiB):
//   [  0, 32)  xpb bf16  (G1 out) -> dead after conv -> yb bf16 (ln out)
//   [ 32, 64)  zb  bf16
//   [ 64, 96)  xcb bf16
//   [ 96,160)  dts fp32 (G3 out) -> y fp32 (scan, in-place)
//       [ 96,112) xb bf16   (dead before G3 writes dts)
//       [112,120) W_inb bf16 (dead before G3)
//   [160,169)  Wcb bf16 (2176x2048: W_dt | W_x | zeros)
//   [169,173)  W_outb bf16
//   [174,175)  Bp, Cp fp32
// ---------------------------------------------------------------------------
extern "C" void kernel_launch(void* const* d_in, const int* in_sizes, int n_in,
                              void* d_out, int out_size, void* d_ws, size_t ws_size,
                              hipStream_t stream)
{
    const float* x      = (const float*)d_in[0];
    const float* W_in   = (const float*)d_in[1];
    const float* conv_w = (const float*)d_in[2];
    const float* conv_b = (const float*)d_in[3];
    const float* W_x    = (const float*)d_in[4];
    const float* W_dt   = (const float*)d_in[5];
    const float* b_dt   = (const float*)d_in[6];
    const float* A_log  = (const float*)d_in[7];
    const float* D_par  = (const float*)d_in[8];
    const float* W_out  = (const float*)d_in[9];
    const float* ln_g   = (const float*)d_in[10];
    const float* ln_b   = (const float*)d_in[11];
    float* out = (float*)d_out;

    char* w = (char*)d_ws;
    const size_t MB = 1ull << 20;
    unsigned short* xpb    = (unsigned short*)(w);
    unsigned short* zb     = (unsigned short*)(w + 32 * MB);
    unsigned short* xcb    = (unsigned short*)(w + 64 * MB);
    float*          dts    = (float*)(w + 96 * MB);
    unsigned short* xb     = (unsigned short*)(w + 96 * MB);
    unsigned short* W_inb  = (unsigned short*)(w + 112 * MB);
    unsigned short* Wcb    = (unsigned short*)(w + 160 * MB);
    unsigned short* W_outb = (unsigned short*)(w + 169 * MB);
    float*          BpF    = (float*)(w + 174 * MB);
    float*          CpF    = BpF + (size_t)BT * DS;
    unsigned short* yb     = xpb;   // reuse after conv

    dim3 blk(256);
    dim3 blk512(512);

    // conversions to bf16
    cvt_bf16<<<dim3((BT * DM / 4 + 255) / 256), blk, 0, stream>>>(x, xb, BT * DM / 4);
    cvt_bf16<<<dim3((2 * DI * DM / 4 + 255) / 256), blk, 0, stream>>>(W_in, W_inb, 2 * DI * DM / 4);
    cvt_wc<<<dim3((NC * DI / 4 + 255) / 256), blk, 0, stream>>>(W_dt, W_x, Wcb);
    cvt_bf16<<<dim3((DM * DI / 4 + 255) / 256), blk, 0, stream>>>(W_out, W_outb, DM * DI / 4);

    // 1) xz = x @ W_in^T -> split bf16 xpb | zb   (npm=32, npn=32)
    gemm_mfma<<<dim3((BT / 256) * (2 * DI / 128)), blk512, 0, stream>>>(
        xb, W_inb, BT, 2 * DI, DM, 0, nullptr, xpb, zb, nullptr);

    // 2) depthwise conv + silu -> xcb bf16
    conv_silu<<<dim3(BT * DI / 256), blk, 0, stream>>>(xpb, conv_w, conv_b, xcb);

    // 3) fused dt+ssm GEMM: [W_dt | W_x] -> dts fp32 (softplus+bias), Bp, Cp
    gemm_mfma<<<dim3((BT / 256) * (NC / 128)), blk512, 0, stream>>>(
        xcb, Wcb, BT, NC, DI, 1, b_dt, dts, BpF, CpF);

    // 4) chunked parallel scan -> y fp32 (in-place over dts)
    scan2<<<dim3(DI / 16, B_SZ), blk, 0, stream>>>(xcb, dts, BpF, CpF, A_log);

    // 5) LayerNorm + residual + gate -> yb bf16
    ln_fuse<<<dim3(BT), blk, 0, stream>>>(dts, xcb, zb, ln_g, ln_b, D_par, yb);

    // 6) out = y @ W_out^T -> fp32
    gemm_mfma<<<dim3((BT / 256) * (DM / 128)), blk512, 0, stream>>>(
        yb, W_outb, BT, DM, DI, 2, nullptr, out, nullptr, nullptr);
}